// Round 7
// baseline (1570.425 us; speedup 1.0000x reference)
//
#include <hip/hip_runtime.h>

#define BATCH 131072

typedef __attribute__((ext_vector_type(8))) __bf16 bf16x8;
typedef __attribute__((ext_vector_type(16))) float f32x16;

__constant__ int FOFF[23] = {0,4,8,12,16,20,24,28,32,36,40,44,48,50,52,53,57,58,59,60,61,62,63};
__constant__ int FDIM[23] = {4,4,4,4,4,4,4,4,4,4,4,4,2,2,1,4,1,1,1,1,1,1,2};

__device__ __forceinline__ unsigned short f2bf(float f){
  unsigned int u = __float_as_uint(f);
  u += 0x7fffu + ((u>>16)&1u);   // RNE
  return (unsigned short)(u>>16);
}
__device__ __forceinline__ unsigned int packpair(float a, float b){
  return (unsigned int)f2bf(a) | ((unsigned int)f2bf(b)<<16);
}
__device__ __forceinline__ float bflo(unsigned int u){ return __uint_as_float(u<<16); }
__device__ __forceinline__ float bfhi(unsigned int u){ return __uint_as_float(u & 0xffff0000u); }

// ---------------- prep: pack W1..W5 into MFMA-B fragment-linear bf16 layout ----------------
__global__ void prep_weights(const float* __restrict__ W1, const float* __restrict__ W2,
    const float* __restrict__ W3, const float* __restrict__ W4, const float* __restrict__ W5,
    unsigned short* __restrict__ wpack){
  int idx = blockIdx.x*256 + threadIdx.x;
  if (idx >= 22656) return;
  const float* W; int rel; int Kd;
  if (idx < 5760){ W = W1; rel = idx; Kd = 230; }
  else {
    int r2 = idx - 5760;
    int li = r2 / 4224; rel = r2 - li*4224; Kd = 164;
    W = (li==0)?W2:((li==1)?W3:((li==2)?W4:W5));
  }
  int lane = rel & 63, rem = rel >> 6;
  int nt = rem % 6, ks = rem / 6;
  int n  = nt*32 + (lane&31);
  int k0 = ks*16 + ((lane>>5)<<3);
  unsigned int v[4];
  #pragma unroll
  for (int p=0;p<4;p++){
    int ka = k0 + 2*p, kb = ka+1;
    float fa = (ka<Kd && n<164) ? W[ka*164+n] : 0.f;
    float fb = (kb<Kd && n<164) ? W[kb*164+n] : 0.f;
    v[p] = packpair(fa, fb);
  }
  *(uint4*)(wpack + (size_t)idx*8) = make_uint4(v[0],v[1],v[2],v[3]);
}

// ================= Kernel A: projection + attention, z -> workspace =================
// 32 samples/block, 256 threads. LDS 34.8 KB -> 4 blocks/CU (16 waves).
// Attention at C=1/task: ~45 live floats -> no spill pressure.
__global__ __launch_bounds__(256, 4) void proj_attn(
    const float* __restrict__ xg, const float* __restrict__ Wproj, const float* __restrict__ bproj,
    const float* __restrict__ Wq, const float* __restrict__ Wk, const float* __restrict__ Wv,
    unsigned int* __restrict__ zg)
{
  // LDS: xb [0,8352) 2088 f32 ; hp [8352,26528) 32*142 u32 ; sw [26528,34848) 2080 f32
  __shared__ __align__(16) unsigned char LDS[34848];
  float* xb = (float*)LDS;
  unsigned int* hp = (unsigned int*)(LDS + 8352);
  float* sw = (float*)(LDS + 26528);

  const int t = threadIdx.x;
  const int S0 = blockIdx.x*32;

  // ---- P0: stage x (float4-coalesced) + pad + small weights ----
  {
    const uint4* src4 = (const uint4*)(xg + (size_t)S0*65);
    uint4* dst4 = (uint4*)xb;
    for (int i=t; i<520; i+=256) dst4[i] = src4[i];
    if (t<8) xb[2080+t] = 0.f;
  }
  for (int idx=t; idx<2080; idx+=256){
    if (idx < 1840){                 // proj packed: [o][0..3]=w, [4]=bias
      int o = idx>>3, u = idx&7;
      int fi = o/10;
      float v = 0.f;
      if (u<4){ if (u < FDIM[fi]) v = Wproj[(FOFF[fi]+u)*230 + o]; }
      else if (u==4) v = bproj[o];
      sw[idx] = v;
    } else if (idx < 1960){          // M = Wq*Wk^T/sqrt(10), [10][12]
      int r = idx-1840, e = r/12, d = r-12*e;
      float v = 0.f;
      if (d<10){ float ssum=0.f;
        #pragma unroll
        for (int k2=0;k2<10;k2++) ssum += Wq[e*10+k2]*Wk[d*10+k2];
        v = ssum*0.31622776601683794f; }
      sw[idx] = v;
    } else {                         // Wv [10][12]
      int r = idx-1960, e = r/12, d = r-12*e;
      sw[idx] = (d<10)? Wv[e*10+d] : 0.f;
    }
  }
  __syncthreads();

  // ---- P1: block-diag projection -> hp[s*142 + j*6 + p] (8B-aligned rows) ----
  for (int L=t; L<3680; L+=256){
    int s = L & 31, jp = L>>5;       // jp in [0,115)
    int j = jp/5, p = jp-5*j;
    int o0 = j*10 + 2*p;
    int roff = FOFF[j];
    const float* wA = sw + o0*8;
    const float* xs = xb + s*65 + roff;
    float a0 = wA[4]  + xs[0]*wA[0] + xs[1]*wA[1] + xs[2]*wA[2]  + xs[3]*wA[3];
    float a1 = wA[12] + xs[0]*wA[8] + xs[1]*wA[9] + xs[2]*wA[10] + xs[3]*wA[11];
    hp[s*142 + j*6 + p] = packpair(a0,a1);
  }
  __syncthreads();

  // ---- P2: attention, one (sample, query-row) per task; 736 tasks ----
  for (int task=t; task<736; task+=256){
    int s = task & 31, i = task >> 5;      // i in [0,23)
    const unsigned int* hrow = hp + s*142;
    // hi
    float hi[10];
    {
      uint2 u01 = *(const uint2*)(hrow + i*6);
      uint2 u23 = *(const uint2*)(hrow + i*6 + 2);
      unsigned int u4 = hrow[i*6+4];
      hi[0]=bflo(u01.x); hi[1]=bfhi(u01.x);
      hi[2]=bflo(u01.y); hi[3]=bfhi(u01.y);
      hi[4]=bflo(u23.x); hi[5]=bfhi(u23.x);
      hi[6]=bflo(u23.y); hi[7]=bfhi(u23.y);
      hi[8]=bflo(u4);    hi[9]=bfhi(u4);
    }
    // g = hi * M
    float g[10];
    #pragma unroll
    for (int d=0;d<10;d++) g[d]=0.f;
    #pragma unroll
    for (int e=0;e<10;e++){
      const float4* mr = (const float4*)(sw + 1840 + e*12);
      float4 m0 = mr[0], m1 = mr[1];
      float2 m2 = *(const float2*)(sw + 1840 + e*12 + 8);
      float he = hi[e];
      g[0]+=he*m0.x; g[1]+=he*m0.y; g[2]+=he*m0.z; g[3]+=he*m0.w;
      g[4]+=he*m1.x; g[5]+=he*m1.y; g[6]+=he*m1.z; g[7]+=he*m1.w;
      g[8]+=he*m2.x; g[9]+=he*m2.y;
    }
    // single-pass unnormalized softmax over 23 keys
    float st[10]; float tau = 0.f;
    #pragma unroll
    for (int d=0;d<10;d++) st[d]=0.f;
    for (int j=0;j<23;j++){
      uint2 u01 = *(const uint2*)(hrow + j*6);
      uint2 u23 = *(const uint2*)(hrow + j*6 + 2);
      unsigned int u4 = hrow[j*6+4];
      float hj[10];
      hj[0]=bflo(u01.x); hj[1]=bfhi(u01.x);
      hj[2]=bflo(u01.y); hj[3]=bfhi(u01.y);
      hj[4]=bflo(u23.x); hj[5]=bfhi(u23.x);
      hj[6]=bflo(u23.y); hj[7]=bfhi(u23.y);
      hj[8]=bflo(u4);    hj[9]=bfhi(u4);
      float l = 0.f;
      #pragma unroll
      for (int d=0;d<10;d++) l += g[d]*hj[d];
      float e = __expf(l);
      tau += e;
      #pragma unroll
      for (int d=0;d<10;d++) st[d] += e*hj[d];
    }
    float inv = __builtin_amdgcn_rcpf(tau);
    // ctx = (st*inv) * Wv
    float ct[10];
    #pragma unroll
    for (int d=0;d<10;d++) ct[d]=0.f;
    #pragma unroll
    for (int e=0;e<10;e++){
      const float4* wr = (const float4*)(sw + 1960 + e*12);
      float4 w0 = wr[0], w1 = wr[1];
      float2 w2 = *(const float2*)(sw + 1960 + e*12 + 8);
      float se = st[e]*inv;
      ct[0]+=se*w0.x; ct[1]+=se*w0.y; ct[2]+=se*w0.z; ct[3]+=se*w0.w;
      ct[4]+=se*w1.x; ct[5]+=se*w1.y; ct[6]+=se*w1.z; ct[7]+=se*w1.w;
      ct[8]+=se*w2.x; ct[9]+=se*w2.y;
    }
    // residual + pack to global z (row pitch 120 u32 = 240 bf16)
    unsigned int* zrow = zg + (size_t)(S0+s)*120 + i*5;
    uint2 r01 = *(const uint2*)(hrow + i*6);
    uint2 r23 = *(const uint2*)(hrow + i*6 + 2);
    unsigned int r4 = hrow[i*6+4];
    zrow[0] = packpair(bflo(r01.x)+ct[0], bfhi(r01.x)+ct[1]);
    zrow[1] = packpair(bflo(r01.y)+ct[2], bfhi(r01.y)+ct[3]);
    zrow[2] = packpair(bflo(r23.x)+ct[4], bfhi(r23.x)+ct[5]);
    zrow[3] = packpair(bflo(r23.y)+ct[6], bfhi(r23.y)+ct[7]);
    zrow[4] = packpair(bflo(r4)+ct[8],   bfhi(r4)+ct[9]);
  }
  // K-pad cols 230..239 (u32 115..119) to zero
  if (t < 160){
    int s = t/5, pc = t-5*s;
    zg[(size_t)(S0+s)*120 + 115 + pc] = 0u;
  }
}

// ---------------- MFMA MLP layer: [64,K]x[K,192] -> relu -> act ----------------
// 8 waves, 12 wave-tiles (2M x 6N). Waves 0-3: 2 N-tiles (same mt), waves 4-7: 1.
template<int KSTEPS>
__device__ __forceinline__ void mlp_layer(const unsigned short* in16, int inPitch,
    const bf16x8* __restrict__ wp, const float* __restrict__ bias,
    unsigned short* out16, int t){
  const int lane = t & 63;
  const int w = t >> 6;            // 0..7
  const int mt = w & 1;
  const int nt0 = w >> 1;          // 0..3
  const bool two = (w < 4);
  const int nt1 = 4 + (w >> 1);
  f32x16 acc0, acc1;
  #pragma unroll
  for (int r=0;r<16;r++){ acc0[r]=0.f; acc1[r]=0.f; }
  const unsigned short* abase = in16 + (mt*32 + (lane&31))*inPitch + ((lane>>5)<<3);
  const bf16x8* wb = wp + lane;
  #pragma unroll
  for (int ks=0; ks<KSTEPS; ++ks){
    bf16x8 a = *(const bf16x8*)(abase + ks*16);
    acc0 = __builtin_amdgcn_mfma_f32_32x32x16_bf16(a, wb[(ks*6+nt0)*64], acc0, 0,0,0);
    if (two)
      acc1 = __builtin_amdgcn_mfma_f32_32x32x16_bf16(a, wb[(ks*6+nt1)*64], acc1, 0,0,0);
  }
  const int colb = (lane&31);
  const int rowb = mt*32 + 4*(lane>>5);
  #pragma unroll
  for (int sel=0; sel<2; ++sel){
    if (sel==1 && !two) break;
    int nt = (sel==0)? nt0 : nt1;
    int n = nt*32 + colb;
    float b = (n<164) ? bias[n] : 0.f;
    f32x16 acc = (sel==0)? acc0 : acc1;
    #pragma unroll
    for (int r=0;r<16;r++){
      int row = rowb + (r&3) + 8*(r>>2);
      float v = fmaxf(acc[r] + b, 0.f);
      out16[row*200 + n] = f2bf(v);
    }
  }
}

// ================= Kernel B: MLP + heads, z <- workspace =================
// 64 samples/block, 512 threads. LDS 59.3 KB -> 2 blocks/CU (16 waves).
__global__ __launch_bounds__(512, 2) void mlp_main(
    const unsigned int* __restrict__ zg,
    const float* __restrict__ b1, const float* __restrict__ b2, const float* __restrict__ b3,
    const float* __restrict__ b4, const float* __restrict__ b5,
    const float* __restrict__ Wmove, const float* __restrict__ bmove,
    const float* __restrict__ Wmark, const float* __restrict__ bmark,
    const unsigned short* __restrict__ wpack, float* __restrict__ out)
{
  // LDS: zb [0,31744) 64*124 u32 (pitch 248 bf16) ; a16 [31744,57344) 64*200 bf16 ;
  //      hwu [57344,59312) 492 u32 head weights
  __shared__ __align__(16) unsigned char LDS[59312];
  unsigned int* zb = (unsigned int*)LDS;
  unsigned short* z16 = (unsigned short*)LDS;
  unsigned short* a16 = (unsigned short*)(LDS + 31744);
  unsigned int* hwu = (unsigned int*)(LDS + 57344);

  const int t = threadIdx.x;
  const int S0 = blockIdx.x*64;

  // ---- stage z tile (coalesced uint4), remap pitch 120 -> 124 u32 ----
  for (int idx=t; idx<1920; idx+=512){
    int s = idx/30, c4 = idx - 30*s;
    ((uint4*)(zb + s*124))[c4] = ((const uint4*)(zg + (size_t)(S0+s)*120))[c4];
  }
  // ---- stage head weights: bf16 pairs [6][82] ----
  if (t < 492){
    int o = t/82, kp = t - 82*o;
    float w0, w1;
    if (o<5){ w0 = Wmove[(2*kp)*5+o]; w1 = Wmove[(2*kp+1)*5+o]; }
    else    { w0 = Wmark[2*kp];       w1 = Wmark[2*kp+1]; }
    hwu[t] = packpair(w0,w1);
  }
  __syncthreads();

  // ---- MLP: 5 MFMA layers, ping-pong LDS ----
  const bf16x8* wpk = (const bf16x8*)wpack;
  mlp_layer<15>(z16, 248, wpk,          b1, a16, t); __syncthreads();
  mlp_layer<11>(a16, 200, wpk + 5760,   b2, z16, t); __syncthreads();
  mlp_layer<11>(z16, 200, wpk + 9984,   b3, a16, t); __syncthreads();
  mlp_layer<11>(a16, 200, wpk + 14208,  b4, z16, t); __syncthreads();
  mlp_layer<11>(z16, 200, wpk + 18432,  b5, a16, t); __syncthreads();

  // ---- heads ----
  {
    const int o = t & 7;
    const int s2 = t >> 3;           // 0..63
    if (o < 6){
      const unsigned int* ar = (const unsigned int*)(a16 + s2*200);
      const unsigned int* wr = hwu + o*82;
      float acc = 0.f;
      for (int kp=0; kp<82; ++kp){
        unsigned int ua = ar[kp], uw = wr[kp];
        acc += bflo(ua)*bflo(uw) + bfhi(ua)*bfhi(uw);
      }
      acc += (o<5)? bmove[o] : bmark[0];
      if (o<5) out[(size_t)(S0+s2)*5 + o] = acc;
      else     out[(size_t)BATCH*5 + S0 + s2] = acc;
    }
  }
}

extern "C" void kernel_launch(void* const* d_in, const int* in_sizes, int n_in,
                              void* d_out, int out_size, void* d_ws, size_t ws_size,
                              hipStream_t stream){
  (void)in_sizes; (void)n_in; (void)out_size; (void)ws_size;
  const float* x     = (const float*)d_in[0];
  const float* Wproj = (const float*)d_in[1];
  const float* bproj = (const float*)d_in[2];
  const float* Wq    = (const float*)d_in[3];
  const float* Wk    = (const float*)d_in[4];
  const float* Wv    = (const float*)d_in[5];
  const float* W1    = (const float*)d_in[6];
  const float* b1    = (const float*)d_in[7];
  const float* W2    = (const float*)d_in[8];
  const float* b2    = (const float*)d_in[9];
  const float* W3    = (const float*)d_in[10];
  const float* b3    = (const float*)d_in[11];
  const float* W4    = (const float*)d_in[12];
  const float* b4    = (const float*)d_in[13];
  const float* W5    = (const float*)d_in[14];
  const float* b5    = (const float*)d_in[15];
  const float* Wmove = (const float*)d_in[16];
  const float* bmove = (const float*)d_in[17];
  const float* Wmark = (const float*)d_in[18];
  const float* bmark = (const float*)d_in[19];

  unsigned short* wpack = (unsigned short*)d_ws;                       // 362,496 B
  unsigned int*   zg    = (unsigned int*)((char*)d_ws + (1<<19));      // 62.9 MB @ +512 KB

  prep_weights<<<89, 256, 0, stream>>>(W1, W2, W3, W4, W5, wpack);
  proj_attn<<<4096, 256, 0, stream>>>(x, Wproj, bproj, Wq, Wk, Wv, zg);
  mlp_main<<<2048, 512, 0, stream>>>(zg, b1, b2, b3, b4, b5,
      Wmove, bmove, Wmark, bmark, wpack, (float*)d_out);
}